// Round 1
// baseline (510.505 us; speedup 1.0000x reference)
//
#include <hip/hip_runtime.h>
#include <hip/hip_bf16.h>

// ---------------------------------------------------------------------------
// MoE conv: y[b] = conv3x3(x[b], sum_j g_j W[e_j]) + sum_j g_j bias[e_j]
// Pipeline: (A) mean over HW -> gate_x ; (B) logits/softmax/top4/loss ;
//           (C) combine weights per batch ; (D) conv with combined weights.
// ---------------------------------------------------------------------------

// ---- Kernel A: gate_x[b][c] = mean(x[b,c,:,:]) ----------------------------
__global__ __launch_bounds__(256) void gatex_kernel(const float* __restrict__ x,
                                                    float* __restrict__ gate_x) {
  int bc = blockIdx.x;  // b*64 + c, 0..1023
  const float4* xp = (const float4*)(x + (size_t)bc * 4096);
  int t = threadIdx.x;
  float s = 0.f;
#pragma unroll
  for (int i = 0; i < 4; ++i) {
    float4 v = xp[t + i * 256];
    s += v.x + v.y + v.z + v.w;
  }
  for (int off = 32; off > 0; off >>= 1) s += __shfl_down(s, off, 64);
  __shared__ float wsum[4];
  int wid = t >> 6, lane = t & 63;
  if (lane == 0) wsum[wid] = s;
  __syncthreads();
  if (t == 0) {
    float tot = wsum[0] + wsum[1] + wsum[2] + wsum[3];
    gate_x[bc] = tot * (1.0f / 4096.0f);
  }
}

// ---- Kernel B: logits -> softmax -> top4 gates -> loss --------------------
__global__ __launch_bounds__(256) void gate_kernel(const float* __restrict__ gate_x,
                                                   const float* __restrict__ w_gate,
                                                   float* __restrict__ tkg,
                                                   int* __restrict__ tki,
                                                   float* __restrict__ loss_out) {
  __shared__ float sl[16][16];   // logits
  __shared__ float sg[16][16];   // gates (dense)
  __shared__ float simp[16], sld[16];
  int t = threadIdx.x;
  int b = t >> 4, e = t & 15;
  float acc = 0.f;
  for (int c = 0; c < 64; ++c) acc += gate_x[b * 64 + c] * w_gate[c * 16 + e];
  sl[b][e] = acc;
  __syncthreads();
  if (t < 16) {
    int bb = t;
    float m = sl[bb][0];
#pragma unroll
    for (int i = 1; i < 16; ++i) m = fmaxf(m, sl[bb][i]);
    float p[16];
    float z = 0.f;
#pragma unroll
    for (int i = 0; i < 16; ++i) { p[i] = expf(sl[bb][i] - m); z += p[i]; }
#pragma unroll
    for (int i = 0; i < 16; ++i) p[i] /= z;
    // stable top-4 (earliest index wins ties, matching lax.top_k)
    int idx[4]; float val[4];
    bool used[16];
#pragma unroll
    for (int i = 0; i < 16; ++i) used[i] = false;
    for (int j = 0; j < 4; ++j) {
      int bi = 0; float bv = -1.f;
      for (int i = 0; i < 16; ++i)
        if (!used[i] && p[i] > bv) { bv = p[i]; bi = i; }
      used[bi] = true; idx[j] = bi; val[j] = bv;
    }
    float ssum = val[0] + val[1] + val[2] + val[3] + 1e-6f;
#pragma unroll
    for (int i = 0; i < 16; ++i) sg[bb][i] = 0.f;
    for (int j = 0; j < 4; ++j) {
      float g = val[j] / ssum;
      sg[bb][idx[j]] = g;
      tkg[bb * 4 + j] = g;
      tki[bb * 4 + j] = idx[j];
    }
  }
  __syncthreads();
  if (t < 16) {
    int ee = t; float imp = 0.f, ld = 0.f;
    for (int bb = 0; bb < 16; ++bb) {
      float g = sg[bb][ee];
      imp += g;
      if (g > 0.f) ld += 1.f;
    }
    simp[ee] = imp; sld[ee] = ld;
  }
  __syncthreads();
  if (t == 0) {
    float mi = 0.f, ml = 0.f;
    for (int i = 0; i < 16; ++i) { mi += simp[i]; ml += sld[i]; }
    mi *= (1.f / 16.f); ml *= (1.f / 16.f);
    float vi = 0.f, vl = 0.f;
    for (int i = 0; i < 16; ++i) {
      float d = simp[i] - mi; vi += d * d;
      float dl = sld[i] - ml; vl += dl * dl;
    }
    vi *= (1.f / 15.f); vl *= (1.f / 15.f);  // ddof=1
    loss_out[0] = (vi / (mi * mi + 1e-10f) + vl / (ml * ml + 1e-10f)) * 0.01f;
  }
}

// ---- Kernel C: combined weights/bias per batch ----------------------------
// wc layout: [b][ci][co][k9]  (so the conv's inner weight scan is contiguous)
__global__ __launch_bounds__(256) void combine_kernel(const float* __restrict__ W,
                                                      const float* __restrict__ bias,
                                                      const float* __restrict__ tkg,
                                                      const int* __restrict__ tki,
                                                      float* __restrict__ wc,
                                                      float* __restrict__ bc) {
  int b = blockIdx.x, t = threadIdx.x;
  __shared__ float g[4];
  __shared__ int e[4];
  if (t < 4) { g[t] = tkg[b * 4 + t]; e[t] = tki[b * 4 + t]; }
  __syncthreads();
  float g0 = g[0], g1 = g[1], g2 = g[2], g3 = g[3];
  int e0 = e[0], e1 = e[1], e2 = e[2], e3 = e[3];
  if (t < 64)
    bc[b * 64 + t] = g0 * bias[e0 * 64 + t] + g1 * bias[e1 * 64 + t] +
                     g2 * bias[e2 * 64 + t] + g3 * bias[e3 * 64 + t];
  for (int o = t; o < 36864; o += 256) {
    int ci = o / 576;
    int rem = o - ci * 576;
    int co = rem / 9;
    int k = rem - co * 9;
    int wi = (co * 64 + ci) * 9 + k;  // W is [e][co][ci][3][3]
    float v = g0 * W[e0 * 36864 + wi] + g1 * W[e1 * 36864 + wi] +
              g2 * W[e2 * 36864 + wi] + g3 * W[e3 * 36864 + wi];
    wc[b * 36864 + o] = v;
  }
}

// ---- Kernel D: conv3x3 with combined weights ------------------------------
// block = (row-tile rt, batch b); 256 threads = 4 rows x 64 cols; acc over all
// 64 Cout in VGPRs; weights via uniform (scalar) loads -> SGPR FMA operand.
__global__ __launch_bounds__(256) void conv_kernel(const float* __restrict__ x,
                                                   const float* __restrict__ wc,
                                                   const float* __restrict__ bc,
                                                   float* __restrict__ y) {
  int rt = blockIdx.x;  // 0..15
  int b = blockIdx.y;   // 0..15
  int t = threadIdx.x;
  int r = t >> 6, c = t & 63;
  int h0 = rt * 4;
  __shared__ float xs[16][6][66];  // [ci_chunk][row -1..+4][col -1..64]
  float acc[64];
#pragma unroll
  for (int i = 0; i < 64; ++i) acc[i] = 0.f;
  const float* wcb = wc + b * 36864;

  for (int cc = 0; cc < 4; ++cc) {
    // stage 16 input channels (6 rows with halo, 66 cols with halo)
    for (int idx = t; idx < 16 * 6 * 66; idx += 256) {
      int cil = idx / 396;
      int rr = (idx / 66) % 6;
      int cp = idx - (idx / 66) * 66;
      int h = h0 + rr - 1, w = cp - 1;
      float v = 0.f;
      if ((unsigned)h < 64u && (unsigned)w < 64u)
        v = x[(((size_t)b * 64 + cc * 16 + cil) * 64 + h) * 64 + w];
      xs[cil][rr][cp] = v;
    }
    __syncthreads();
    for (int cil = 0; cil < 16; ++cil) {
      float xv[9];
#pragma unroll
      for (int dr = 0; dr < 3; ++dr)
#pragma unroll
        for (int dc = 0; dc < 3; ++dc)
          xv[dr * 3 + dc] = xs[cil][r + dr][c + dc];
      const float* wrow = wcb + (cc * 16 + cil) * 576;  // uniform -> s_load
#pragma unroll
      for (int co = 0; co < 64; ++co) {
#pragma unroll
        for (int k = 0; k < 9; ++k)
          acc[co] = fmaf(xv[k], wrow[co * 9 + k], acc[co]);
      }
    }
    __syncthreads();
  }
  int h = h0 + r;
#pragma unroll
  for (int co = 0; co < 64; ++co)
    y[(((size_t)b * 64 + co) * 64 + h) * 64 + c] = acc[co] + bc[b * 64 + co];
}

// ---------------------------------------------------------------------------
extern "C" void kernel_launch(void* const* d_in, const int* in_sizes, int n_in,
                              void* d_out, int out_size, void* d_ws, size_t ws_size,
                              hipStream_t stream) {
  const float* x = (const float*)d_in[0];       // (16,64,64,64)
  const float* w_gate = (const float*)d_in[1];  // (64,16)
  // d_in[2] w_noise unused (train==0 path)
  const float* W = (const float*)d_in[3];       // (16,64,64,3,3)
  const float* bias = (const float*)d_in[4];    // (16,64)
  float* out = (float*)d_out;                   // y (4194304) ++ loss (1)
  float* ws = (float*)d_ws;

  float* gate_x = ws;                  // 1024
  float* tkg = ws + 1024;              // 64
  int* tki = (int*)(ws + 1088);        // 64
  float* bc = ws + 1152;               // 1024
  float* wc = ws + 2176;               // 589824

  gatex_kernel<<<1024, 256, 0, stream>>>(x, gate_x);
  gate_kernel<<<1, 256, 0, stream>>>(gate_x, w_gate, tkg, tki, out + 4194304);
  combine_kernel<<<16, 256, 0, stream>>>(W, bias, tkg, tki, wc, bc);
  dim3 grid(16, 16);
  conv_kernel<<<grid, 256, 0, stream>>>(x, wc, bc, out);
}

// Round 2
// 123.961 us; speedup vs baseline: 4.1183x; 4.1183x over previous
//
#include <hip/hip_runtime.h>
#include <hip/hip_bf16.h>

// ---------------------------------------------------------------------------
// MoE conv via combined-weight trick + bf16 MFMA:
//   y[b] = conv3x3(x[b], sum_j g_j W[e_j]) + sum_j g_j bias[e_j]
// Pipeline:
//   A gatex:     gate_x[b][c] = mean_{hw} x
//   B gate:      softmax -> top4 -> gates, aux loss
//   C combine:   wc[b][co][p][ci] (bf16), bc[b][co] (fp32)
//   T transpose: xt[b][h][w][ci] (bf16, ci innermost for MFMA B-frags)
//   D conv_mfma: 9 shifted K=64 GEMMs with mfma_f32_16x16x32_bf16
// ---------------------------------------------------------------------------

typedef __attribute__((ext_vector_type(8))) short bf16x8;
typedef __attribute__((ext_vector_type(4))) float f32x4;

__device__ inline unsigned short f2bf(float f) {
  unsigned u = __builtin_bit_cast(unsigned, f);
  unsigned r = u + 0x7FFFu + ((u >> 16) & 1u);
  return (unsigned short)(r >> 16);
}

// ---- Kernel A: gate_x[b][c] = mean(x[b,c,:,:]) ----------------------------
__global__ __launch_bounds__(256) void gatex_kernel(const float* __restrict__ x,
                                                    float* __restrict__ gate_x) {
  int bc = blockIdx.x;  // b*64 + c
  const float4* xp = (const float4*)(x + (size_t)bc * 4096);
  int t = threadIdx.x;
  float s = 0.f;
#pragma unroll
  for (int i = 0; i < 4; ++i) {
    float4 v = xp[t + i * 256];
    s += v.x + v.y + v.z + v.w;
  }
  for (int off = 32; off > 0; off >>= 1) s += __shfl_down(s, off, 64);
  __shared__ float wsum[4];
  int wid = t >> 6, lane = t & 63;
  if (lane == 0) wsum[wid] = s;
  __syncthreads();
  if (t == 0) gate_x[bc] = (wsum[0] + wsum[1] + wsum[2] + wsum[3]) * (1.0f / 4096.0f);
}

// ---- Kernel B: logits -> softmax -> top4 gates -> loss --------------------
__global__ __launch_bounds__(256) void gate_kernel(const float* __restrict__ gate_x,
                                                   const float* __restrict__ w_gate,
                                                   float* __restrict__ tkg,
                                                   int* __restrict__ tki,
                                                   float* __restrict__ loss_out) {
  __shared__ float sl[16][16];
  __shared__ float sg[16][16];
  __shared__ float simp[16], sld[16];
  int t = threadIdx.x;
  int b = t >> 4, e = t & 15;
  float acc = 0.f;
  for (int c = 0; c < 64; ++c) acc += gate_x[b * 64 + c] * w_gate[c * 16 + e];
  sl[b][e] = acc;
  __syncthreads();
  if (t < 16) {
    int bb = t;
    float m = sl[bb][0];
#pragma unroll
    for (int i = 1; i < 16; ++i) m = fmaxf(m, sl[bb][i]);
    float p[16];
    float z = 0.f;
#pragma unroll
    for (int i = 0; i < 16; ++i) { p[i] = expf(sl[bb][i] - m); z += p[i]; }
#pragma unroll
    for (int i = 0; i < 16; ++i) p[i] /= z;
    int idx[4]; float val[4];
    bool used[16];
#pragma unroll
    for (int i = 0; i < 16; ++i) used[i] = false;
    for (int j = 0; j < 4; ++j) {
      int bi = 0; float bv = -1.f;
      for (int i = 0; i < 16; ++i)
        if (!used[i] && p[i] > bv) { bv = p[i]; bi = i; }
      used[bi] = true; idx[j] = bi; val[j] = bv;
    }
    float ssum = val[0] + val[1] + val[2] + val[3] + 1e-6f;
#pragma unroll
    for (int i = 0; i < 16; ++i) sg[bb][i] = 0.f;
    for (int j = 0; j < 4; ++j) {
      float g = val[j] / ssum;
      sg[bb][idx[j]] = g;
      tkg[bb * 4 + j] = g;
      tki[bb * 4 + j] = idx[j];
    }
  }
  __syncthreads();
  if (t < 16) {
    int ee = t; float imp = 0.f, ld = 0.f;
    for (int bb = 0; bb < 16; ++bb) {
      float g = sg[bb][ee];
      imp += g;
      if (g > 0.f) ld += 1.f;
    }
    simp[ee] = imp; sld[ee] = ld;
  }
  __syncthreads();
  if (t == 0) {
    float mi = 0.f, ml = 0.f;
    for (int i = 0; i < 16; ++i) { mi += simp[i]; ml += sld[i]; }
    mi *= (1.f / 16.f); ml *= (1.f / 16.f);
    float vi = 0.f, vl = 0.f;
    for (int i = 0; i < 16; ++i) {
      float d = simp[i] - mi; vi += d * d;
      float dl = sld[i] - ml; vl += dl * dl;
    }
    vi *= (1.f / 15.f); vl *= (1.f / 15.f);
    loss_out[0] = (vi / (mi * mi + 1e-10f) + vl / (ml * ml + 1e-10f)) * 0.01f;
  }
}

// ---- Kernel C: combined weights (bf16, [b][co][p][ci]) + bias -------------
__global__ __launch_bounds__(256) void combine_kernel(const float* __restrict__ W,
                                                      const float* __restrict__ bias,
                                                      const float* __restrict__ tkg,
                                                      const int* __restrict__ tki,
                                                      unsigned short* __restrict__ wc,
                                                      float* __restrict__ bc) {
  int cg = blockIdx.x;  // co group of 4
  int b = blockIdx.y;
  int t = threadIdx.x;
  __shared__ float g[4];
  __shared__ int e[4];
  if (t < 4) { g[t] = tkg[b * 4 + t]; e[t] = tki[b * 4 + t]; }
  __syncthreads();
  float g0 = g[0], g1 = g[1], g2 = g[2], g3 = g[3];
  int e0 = e[0], e1 = e[1], e2 = e[2], e3 = e[3];
  if (cg == 0 && t < 64)
    bc[b * 64 + t] = g0 * bias[e0 * 64 + t] + g1 * bias[e1 * 64 + t] +
                     g2 * bias[e2 * 64 + t] + g3 * bias[e3 * 64 + t];
  for (int idx = t; idx < 2304; idx += 256) {
    int col = idx / 576;          // 0..3
    int rem = idx - col * 576;
    int p = rem >> 6;             // 0..8
    int ci = rem & 63;
    int co = cg * 4 + col;
    int wi = (co * 64 + ci) * 9 + p;  // W: [e][co][ci][3][3]
    float v = g0 * W[e0 * 36864 + wi] + g1 * W[e1 * 36864 + wi] +
              g2 * W[e2 * 36864 + wi] + g3 * W[e3 * 36864 + wi];
    wc[((b * 64 + co) * 9 + p) * 64 + ci] = f2bf(v);
  }
}

// ---- Kernel T: xt[b][h][w][ci] (bf16) from x[b][ci][h][w] (f32) -----------
__global__ __launch_bounds__(256) void transpose_kernel(const float* __restrict__ x,
                                                        unsigned short* __restrict__ xt) {
  int bh = blockIdx.x;  // b*64 + h
  int b = bh >> 6, h = bh & 63;
  __shared__ float tile[64][65];
  int t = threadIdx.x;
  int w = t & 63, c0 = t >> 6;
#pragma unroll
  for (int i = 0; i < 16; ++i) {
    int ci = c0 * 16 + i;
    tile[ci][w] = x[(((size_t)b * 64 + ci) * 64 + h) * 64 + w];
  }
  __syncthreads();
#pragma unroll
  for (int it = 0; it < 2; ++it) {
    int idx = t + it * 256;   // 0..511
    int wo = idx >> 3;        // 0..63
    int cgi = (idx & 7) * 8;  // ci0
    bf16x8 v;
#pragma unroll
    for (int j = 0; j < 8; ++j)
      v[j] = (short)f2bf(tile[cgi + j][wo]);
    *(bf16x8*)(xt + ((((size_t)b * 64 + h) * 64 + wo) * 64 + cgi)) = v;
  }
}

// ---- Kernel D: conv via 9 shifted K=64 bf16 MFMA GEMMs --------------------
// grid (32 row-pairs, 16 b); 4 waves/block; wave = 64 co x 32 pixels.
__global__ __launch_bounds__(256) void conv_mfma(const unsigned short* __restrict__ xt,
                                                 const unsigned short* __restrict__ wc,
                                                 const float* __restrict__ bc,
                                                 float* __restrict__ y) {
  int rt = blockIdx.x;  // 0..31
  int b = blockIdx.y;   // 0..15
  int tid = threadIdx.x;
  int wv = tid >> 6, L = tid & 63;
  int lane15 = L & 15, quad = L >> 4;
  int row = rt * 2 + (wv >> 1);
  int colbase = (wv & 1) * 32;
  const unsigned short* xtb = xt + ((size_t)b << 18);
  const unsigned short* wcb = wc + (size_t)b * 36864;
  f32x4 acc[4][2];
#pragma unroll
  for (int mt = 0; mt < 4; ++mt)
#pragma unroll
    for (int nt = 0; nt < 2; ++nt) acc[mt][nt] = (f32x4){0.f, 0.f, 0.f, 0.f};
  const bf16x8 zero = {0, 0, 0, 0, 0, 0, 0, 0};
#pragma unroll
  for (int p = 0; p < 9; ++p) {
    int dr = p / 3, dc = p % 3;
    int h = row + dr - 1;
    bool hok = (unsigned)h < 64u;
#pragma unroll
    for (int ck = 0; ck < 2; ++ck) {
      int kb = ck * 32 + quad * 8;
      bf16x8 bf[2];
#pragma unroll
      for (int nt = 0; nt < 2; ++nt) {
        int w = colbase + nt * 16 + lane15 + dc - 1;
        bf16x8 v = zero;
        if (hok && (unsigned)w < 64u)
          v = *(const bf16x8*)(xtb + (((h << 6) + w) << 6) + kb);
        bf[nt] = v;
      }
      bf16x8 af[4];
#pragma unroll
      for (int mt = 0; mt < 4; ++mt) {
        int co = mt * 16 + lane15;
        af[mt] = *(const bf16x8*)(wcb + (co * 9 + p) * 64 + kb);
      }
#pragma unroll
      for (int mt = 0; mt < 4; ++mt)
#pragma unroll
        for (int nt = 0; nt < 2; ++nt)
          acc[mt][nt] = __builtin_amdgcn_mfma_f32_16x16x32_bf16(af[mt], bf[nt], acc[mt][nt], 0, 0, 0);
    }
  }
#pragma unroll
  for (int mt = 0; mt < 4; ++mt) {
#pragma unroll
    for (int r = 0; r < 4; ++r) {
      int co = mt * 16 + quad * 4 + r;
      float bias = bc[(b << 6) + co];
#pragma unroll
      for (int nt = 0; nt < 2; ++nt) {
        int w = colbase + nt * 16 + lane15;
        y[(((size_t)(b << 6) + co) << 12) + (row << 6) + w] = acc[mt][nt][r] + bias;
      }
    }
  }
}

// ---------------------------------------------------------------------------
extern "C" void kernel_launch(void* const* d_in, const int* in_sizes, int n_in,
                              void* d_out, int out_size, void* d_ws, size_t ws_size,
                              hipStream_t stream) {
  const float* x = (const float*)d_in[0];       // (16,64,64,64)
  const float* w_gate = (const float*)d_in[1];  // (64,16)
  const float* W = (const float*)d_in[3];       // (16,64,64,3,3)
  const float* bias = (const float*)d_in[4];    // (16,64)
  float* out = (float*)d_out;                   // y (4194304) ++ loss (1)
  float* ws = (float*)d_ws;

  float* gate_x = ws;                         // 1024 f
  float* tkg = ws + 1024;                     // 64 f
  int* tki = (int*)(ws + 1088);               // 64 i
  float* bc = ws + 1152;                      // 1024 f
  unsigned short* wc = (unsigned short*)(ws + 2176);    // 589824 bf16 (1.18 MB)
  unsigned short* xt = (unsigned short*)(ws + 297088);  // 4194304 bf16 (8.39 MB)

  gatex_kernel<<<1024, 256, 0, stream>>>(x, gate_x);
  transpose_kernel<<<1024, 256, 0, stream>>>(x, xt);
  gate_kernel<<<1, 256, 0, stream>>>(gate_x, w_gate, tkg, tki, out + 4194304);
  {
    dim3 grid(16, 16);
    combine_kernel<<<grid, 256, 0, stream>>>(W, bias, tkg, tki, wc, bc);
  }
  {
    dim3 grid(32, 16);
    conv_mfma<<<grid, 256, 0, stream>>>(xt, wc, bc, out);
  }
}